// Round 4
// baseline (2350.672 us; speedup 1.0000x reference)
//
#include <hip/hip_runtime.h>

#define NUM_ROUTED 7
#define DD 2048
#define HH 2048
#define NTOK 8192

typedef _Float16 f16x8 __attribute__((ext_vector_type(8)));
typedef float f32x4 __attribute__((ext_vector_type(4)));

#define MFMA16(a, b, c) __builtin_amdgcn_mfma_f32_16x16x32_f16((a), (b), (c), 0, 0, 0)

__device__ __forceinline__ unsigned short f2h(float f) {
  union { _Float16 h; unsigned short u; } c;
  c.h = (_Float16)f;
  return c.u;
}

__device__ __forceinline__ void gload16(const void* g, void* l) {
  __builtin_amdgcn_global_load_lds((const __attribute__((address_space(1))) unsigned int*)g,
                                   (__attribute__((address_space(3))) unsigned int*)l,
                                   16, 0, 0);
}

// ---------------------------------------------------------------- gw transpose: [2048][7] -> [7][2048]
__global__ void gwt_kernel(const float* __restrict__ gw, float* __restrict__ gwT) {
  int i = blockIdx.x * 256 + threadIdx.x;  // 56 blocks * 256 = 14336 exact
  float v = gw[i];
  int d = i / NUM_ROUTED;
  int e = i - d * NUM_ROUTED;
  gwT[e * DD + d] = v;
}

// ---------------------------------------------------------------- gate (4 waves/block, 4 tokens/wave)
__global__ void gate_kernel(const float* __restrict__ x, const float* __restrict__ gwT,
                            const float* __restrict__ gb, const float* __restrict__ bias,
                            int* __restrict__ counts, int* __restrict__ tok_list,
                            float* __restrict__ tok_w) {
  __shared__ int lhist[NUM_ROUTED];
  __shared__ int lbase[NUM_ROUTED];
  __shared__ int ent_e[48];
  __shared__ int ent_pos[48];
  __shared__ int ent_t[48];
  __shared__ float ent_w[48];

  const int tid = threadIdx.x;
  const int wave = tid >> 6;
  const int lane = tid & 63;
  if (tid < NUM_ROUTED) lhist[tid] = 0;
  __syncthreads();

  for (int j = 0; j < 4; ++j) {
    const int t = blockIdx.x * 16 + wave * 4 + j;
    const float* xr = x + (size_t)t * DD;
    float acc[NUM_ROUTED] = {0.f, 0.f, 0.f, 0.f, 0.f, 0.f, 0.f};
#pragma unroll
    for (int it = 0; it < 8; ++it) {
      const int d0 = it * 256 + lane * 4;
      float4 xv = *(const float4*)(xr + d0);
#pragma unroll
      for (int e = 0; e < NUM_ROUTED; ++e) {
        float4 g = *(const float4*)(gwT + e * DD + d0);
        acc[e] += xv.x * g.x + xv.y * g.y + xv.z * g.z + xv.w * g.w;
      }
    }
#pragma unroll
    for (int off = 32; off > 0; off >>= 1)
#pragma unroll
      for (int e = 0; e < NUM_ROUTED; ++e) acc[e] += __shfl_down(acc[e], off);
    if (lane == 0) {
      float l[NUM_ROUTED], p[NUM_ROUTED], b[NUM_ROUTED];
      float m = -1e30f;
#pragma unroll
      for (int e = 0; e < NUM_ROUTED; ++e) { l[e] = acc[e] + gb[e]; m = fmaxf(m, l[e]); }
      float s = 0.f;
#pragma unroll
      for (int e = 0; e < NUM_ROUTED; ++e) { p[e] = __expf(l[e] - m); s += p[e]; }
      float inv = 1.f / s;
#pragma unroll
      for (int e = 0; e < NUM_ROUTED; ++e) { p[e] *= inv; b[e] = p[e] + bias[e]; }
      int id[3]; float w[3]; float wsum = 0.f;
      bool used[NUM_ROUTED] = {false, false, false, false, false, false, false};
#pragma unroll
      for (int k = 0; k < 3; ++k) {
        int best = -1; float bv = -1e30f;
#pragma unroll
        for (int e = 0; e < NUM_ROUTED; ++e)
          if (!used[e] && b[e] > bv) { bv = b[e]; best = e; }
        used[best] = true; id[k] = best; w[k] = p[best]; wsum += w[k];
      }
      float wn = 1.f / wsum;
#pragma unroll
      for (int k = 0; k < 3; ++k) {
        int e = id[k];
        int pos = atomicAdd(&lhist[e], 1);
        int slot = (wave * 4 + j) * 3 + k;
        ent_e[slot] = e; ent_pos[slot] = pos; ent_t[slot] = t; ent_w[slot] = w[k] * wn;
      }
    }
  }
  __syncthreads();
  if (tid < NUM_ROUTED) lbase[tid] = atomicAdd(&counts[tid], lhist[tid]);
  __syncthreads();
  if (tid < 48) {
    int e = ent_e[tid];
    int pdst = lbase[e] + ent_pos[tid];
    tok_list[e * NTOK + pdst] = ent_t[tid];
    tok_w[e * NTOK + pdst] = ent_w[tid];
  }
}

// ---------------------------------------------------------------- x fp32 -> fp16
__global__ void split_x_kernel(const float* __restrict__ x, unsigned short* __restrict__ xh) {
  size_t i = ((size_t)blockIdx.x * 256 + threadIdx.x) * 4;
  float4 v = *(const float4*)(x + i);
  ushort4 h;
  h.x = f2h(v.x); h.y = f2h(v.y); h.z = f2h(v.z); h.w = f2h(v.w);
  *(ushort4*)(xh + i) = h;
}

// ---------------------------------------------------------------- transpose+convert 3 weight mats (2048x2048)
__global__ void split3_kernel(const float* __restrict__ s0, const float* __restrict__ s1,
                              const float* __restrict__ s2,
                              unsigned short* __restrict__ d0, unsigned short* __restrict__ d1,
                              unsigned short* __restrict__ d2) {
  const float* src = (blockIdx.z == 0) ? s0 : (blockIdx.z == 1) ? s1 : s2;
  unsigned short* dh = (blockIdx.z == 0) ? d0 : (blockIdx.z == 1) ? d1 : d2;
  __shared__ float t[64][65];
  const int tc = threadIdx.x & 15;   // col/4
  const int tr = threadIdx.x >> 4;   // row (16 per pass)
  const int r0 = blockIdx.y * 64, c0 = blockIdx.x * 64;
#pragma unroll
  for (int p = 0; p < 4; ++p) {
    int r = tr + p * 16;
    float4 v = *(const float4*)(src + (size_t)(r0 + r) * 2048 + c0 + tc * 4);
    t[r][tc * 4 + 0] = v.x;
    t[r][tc * 4 + 1] = v.y;
    t[r][tc * 4 + 2] = v.z;
    t[r][tc * 4 + 3] = v.w;
  }
  __syncthreads();
#pragma unroll
  for (int p = 0; p < 4; ++p) {
    int c = tr + p * 16;  // output row (= source col)
    ushort4 o4;
    o4.x = f2h(t[tc * 4 + 0][c]);
    o4.y = f2h(t[tc * 4 + 1][c]);
    o4.z = f2h(t[tc * 4 + 2][c]);
    o4.w = f2h(t[tc * 4 + 3][c]);
    *(ushort4*)(dh + (size_t)(c0 + c) * 2048 + r0 + tc * 4) = o4;
  }
}

// ---------------------------------------------------------------- GEMM1: x @ (W1 | Wg) + SwiGLU -> act
// 512 threads, 8 waves (2m x 4n); tile 128x128; per-wave 64x32 per accumulator set.
template <bool GATHER>
__global__ __launch_bounds__(512, 4) void gemm1_kernel(
    const unsigned short* __restrict__ xh, const unsigned short* __restrict__ b1_g,
    const unsigned short* __restrict__ bg_g, const int* __restrict__ count,
    const int* __restrict__ tok_list, unsigned short* __restrict__ act) {
  const int n_rows = GATHER ? *count : NTOK;
  const int row0 = blockIdx.x * 128;
  if (row0 >= n_rows) return;
  const int n0 = blockIdx.y * 128;

  __shared__ alignas(16) unsigned short Ah[128 * 64];
  __shared__ alignas(16) unsigned short B1h[128 * 64];
  __shared__ alignas(16) unsigned short Bgh[128 * 64];

  const int tid = threadIdx.x;
  const int lane = tid & 63;
  const int wid = tid >> 6;
  const int wm = (wid >> 2) * 64;   // m-half
  const int wn = (wid & 3) * 32;    // n-quarter

  // staging: thread covers 16B at (row = tid>>3 [+64], col = (tid&7)*8)
  const int sxr = tid >> 3;
  const int sxc = (tid & 7) * 8;
  int ga0, ga1;
  if (GATHER) {
    int r0i = row0 + sxr;
    int r1i = row0 + 64 + sxr;
    ga0 = tok_list[r0i < n_rows ? r0i : n_rows - 1] * DD + sxc;
    ga1 = tok_list[r1i < n_rows ? r1i : n_rows - 1] * DD + sxc;
  } else {
    ga0 = (row0 + sxr) * DD + sxc;
    ga1 = (row0 + 64 + sxr) * DD + sxc;
  }
  const int gb0 = (n0 + sxr) * DD + sxc;
  const int gb1 = (n0 + 64 + sxr) * DD + sxc;
  const int ls0 = tid * 8;          // element offset; bytes = tid*16 (lane-linear)
  const int ls1 = ls0 + 64 * 64;

  f32x4 acc1[4][2] = {};
  f32x4 accg[4][2] = {};

  const int l15 = lane & 15;
  const int khalf = (lane >> 4) * 8;

  for (int k0 = 0; k0 < DD; k0 += 64) {
    gload16(xh + ga0 + k0, &Ah[ls0]);
    gload16(xh + ga1 + k0, &Ah[ls1]);
    gload16(b1_g + gb0 + k0, &B1h[ls0]);
    gload16(b1_g + gb1 + k0, &B1h[ls1]);
    gload16(bg_g + gb0 + k0, &Bgh[ls0]);
    gload16(bg_g + gb1 + k0, &Bgh[ls1]);
    __syncthreads();
#pragma unroll
    for (int ks = 0; ks < 2; ++ks) {
      const int ko = ks * 32 + khalf;
      f16x8 a_h[4];
#pragma unroll
      for (int mi = 0; mi < 4; ++mi)
        a_h[mi] = *(const f16x8*)&Ah[(wm + mi * 16 + l15) * 64 + ko];
      f16x8 u1[2], ug[2];
#pragma unroll
      for (int ni = 0; ni < 2; ++ni) {
        u1[ni] = *(const f16x8*)&B1h[(wn + ni * 16 + l15) * 64 + ko];
        ug[ni] = *(const f16x8*)&Bgh[(wn + ni * 16 + l15) * 64 + ko];
      }
#pragma unroll
      for (int mi = 0; mi < 4; ++mi)
#pragma unroll
        for (int ni = 0; ni < 2; ++ni) {
          acc1[mi][ni] = MFMA16(a_h[mi], u1[ni], acc1[mi][ni]);
          accg[mi][ni] = MFMA16(a_h[mi], ug[ni], accg[mi][ni]);
        }
    }
    __syncthreads();
  }
  // SwiGLU epilogue -> act fp16
#pragma unroll
  for (int mi = 0; mi < 4; ++mi)
#pragma unroll
    for (int ni = 0; ni < 2; ++ni)
#pragma unroll
      for (int r = 0; r < 4; ++r) {
        int m = wm + mi * 16 + (lane >> 4) * 4 + r;
        int nn = wn + ni * 16 + l15;
        float h1 = acc1[mi][ni][r];
        float hg = accg[mi][ni][r];
        float a = (h1 / (1.f + __expf(-h1))) * hg;  // silu(h1)*hg
        act[(row0 + m) * HH + n0 + nn] = f2h(a);
      }
}

// ---------------------------------------------------------------- GEMM2: act @ W2 -> out (m103 config)
// 256 threads, 4 waves (2x2); tile 128x128; per-wave 64x64.
template <bool ROUTED>
__global__ __launch_bounds__(256, 3) void gemm2_kernel(
    const unsigned short* __restrict__ ah, const unsigned short* __restrict__ bh_g,
    const int* __restrict__ count, const int* __restrict__ tok_list,
    const float* __restrict__ tok_w, float* __restrict__ out) {
  const int n_rows = ROUTED ? *count : NTOK;
  const int row0 = blockIdx.x * 128;
  if (row0 >= n_rows) return;
  const int n0 = blockIdx.y * 128;

  __shared__ alignas(16) unsigned short Ah[128 * 64];
  __shared__ alignas(16) unsigned short Bh[128 * 64];

  const int tid = threadIdx.x;
  const int lane = tid & 63;
  const int wid = tid >> 6;
  const int wm = (wid >> 1) * 64;
  const int wn = (wid & 1) * 64;

  const int sxr = tid >> 3;          // 0..31
  const int sxc = (tid & 7) * 8;
  int ga[4], gb[4], ls[4];
#pragma unroll
  for (int p = 0; p < 4; ++p) {
    ga[p] = (row0 + p * 32 + sxr) * HH + sxc;   // act rows in-buffer even past n_rows (finite poison)
    gb[p] = (n0 + p * 32 + sxr) * HH + sxc;
    ls[p] = p * 32 * 64 + tid * 8;
  }

  f32x4 acc[4][4] = {};
  const int l15 = lane & 15;
  const int khalf = (lane >> 4) * 8;

  for (int k0 = 0; k0 < HH; k0 += 64) {
#pragma unroll
    for (int p = 0; p < 4; ++p) gload16(ah + ga[p] + k0, &Ah[ls[p]]);
#pragma unroll
    for (int p = 0; p < 4; ++p) gload16(bh_g + gb[p] + k0, &Bh[ls[p]]);
    __syncthreads();
#pragma unroll
    for (int ks = 0; ks < 2; ++ks) {
      const int ko = ks * 32 + khalf;
      f16x8 a_h[4];
#pragma unroll
      for (int mi = 0; mi < 4; ++mi)
        a_h[mi] = *(const f16x8*)&Ah[(wm + mi * 16 + l15) * 64 + ko];
      f16x8 b_h[4];
#pragma unroll
      for (int ni = 0; ni < 4; ++ni)
        b_h[ni] = *(const f16x8*)&Bh[(wn + ni * 16 + l15) * 64 + ko];
#pragma unroll
      for (int mi = 0; mi < 4; ++mi)
#pragma unroll
        for (int ni = 0; ni < 4; ++ni)
          acc[mi][ni] = MFMA16(a_h[mi], b_h[ni], acc[mi][ni]);
    }
    __syncthreads();
  }
#pragma unroll
  for (int mi = 0; mi < 4; ++mi)
#pragma unroll
    for (int ni = 0; ni < 4; ++ni)
#pragma unroll
      for (int r = 0; r < 4; ++r) {
        int m = wm + mi * 16 + (lane >> 4) * 4 + r;
        int nn = wn + ni * 16 + l15;
        int rg = row0 + m;
        float val = acc[mi][ni][r];
        if (ROUTED) {
          if (rg < n_rows) {
            int t = tok_list[rg];
            float w = tok_w[rg];
            out[t * DD + n0 + nn] += w * val;  // unique (t,col) per launch; stream-ordered
          }
        } else {
          out[rg * DD + n0 + nn] = val;
        }
      }
}

// ---------------------------------------------------------------- launch
extern "C" void kernel_launch(void* const* d_in, const int* in_sizes, int n_in,
                              void* d_out, int out_size, void* d_ws, size_t ws_size,
                              hipStream_t stream) {
  const float* x    = (const float*)d_in[0];
  const float* W1   = (const float*)d_in[1];
  const float* Wg   = (const float*)d_in[2];
  const float* W2   = (const float*)d_in[3];
  const float* Ws1  = (const float*)d_in[4];
  const float* Wsg  = (const float*)d_in[5];
  const float* Ws2  = (const float*)d_in[6];
  const float* gw   = (const float*)d_in[7];
  const float* gb   = (const float*)d_in[8];
  const float* bias = (const float*)d_in[9];
  float* out = (float*)d_out;

  char* p = (char*)d_ws;
  size_t off = 0;
  auto alloc = [&](size_t bytes) {
    void* r = p + off;
    off = (off + bytes + 255) & ~(size_t)255;
    return r;
  };
  int* counts         = (int*)alloc(32);
  int* tok_list       = (int*)alloc((size_t)NUM_ROUTED * NTOK * 4);
  float* tok_w        = (float*)alloc((size_t)NUM_ROUTED * NTOK * 4);
  float* gwT          = (float*)alloc((size_t)NUM_ROUTED * DD * 4);
  unsigned short* xh  = (unsigned short*)alloc((size_t)NTOK * DD * 2);
  unsigned short* b1  = (unsigned short*)alloc((size_t)DD * HH * 2);
  unsigned short* bg  = (unsigned short*)alloc((size_t)DD * HH * 2);
  unsigned short* b2  = (unsigned short*)alloc((size_t)HH * DD * 2);
  unsigned short* act = (unsigned short*)alloc((size_t)NTOK * HH * 2);
  if (off > ws_size) return;  // workspace too small — fail loudly via validation

  hipMemsetAsync(counts, 0, 32, stream);
  gwt_kernel<<<56, 256, 0, stream>>>(gw, gwT);
  gate_kernel<<<NTOK / 16, 256, 0, stream>>>(x, gwT, gb, bias, counts, tok_list, tok_w);
  split_x_kernel<<<(NTOK * DD / 4) / 256, 256, 0, stream>>>(x, xh);

  // shared expert: plain store covers all of out (no memset needed)
  split3_kernel<<<dim3(32, 32, 3), 256, 0, stream>>>(Ws1, Wsg, Ws2, b1, bg, b2);
  gemm1_kernel<false><<<dim3(64, 16), 512, 0, stream>>>(xh, b1, bg, nullptr, nullptr, act);
  gemm2_kernel<false><<<dim3(64, 16), 256, 0, stream>>>(act, b2, nullptr, nullptr, nullptr, out);

  for (int e = 0; e < NUM_ROUTED; ++e) {
    size_t wo = (size_t)e * DD * HH;
    split3_kernel<<<dim3(32, 32, 3), 256, 0, stream>>>(W1 + wo, Wg + wo, W2 + wo, b1, bg, b2);
    gemm1_kernel<true><<<dim3(64, 16), 512, 0, stream>>>(xh, b1, bg, counts + e,
                                                         tok_list + e * NTOK, act);
    gemm2_kernel<true><<<dim3(64, 16), 256, 0, stream>>>(act, b2, counts + e,
                                                         tok_list + e * NTOK,
                                                         tok_w + e * NTOK, out);
  }
}

// Round 7
// 2038.669 us; speedup vs baseline: 1.1530x; 1.1530x over previous
//
#include <hip/hip_runtime.h>

#define NUM_ROUTED 7
#define DD 2048
#define HH 2048
#define NTOK 8192

#define BM 128
#define BN 64
#define BK 64

typedef _Float16 f16x8 __attribute__((ext_vector_type(8)));
typedef float f32x4 __attribute__((ext_vector_type(4)));

#define MFMA16(a, b, c) __builtin_amdgcn_mfma_f32_16x16x32_f16((a), (b), (c), 0, 0, 0)

__device__ __forceinline__ unsigned short f2h(float f) {
  union { _Float16 h; unsigned short u; } c;
  c.h = (_Float16)f;
  return c.u;
}

__device__ __forceinline__ void gload16(const void* g, void* l) {
  __builtin_amdgcn_global_load_lds((const __attribute__((address_space(1))) unsigned int*)g,
                                   (__attribute__((address_space(3))) unsigned int*)l,
                                   16, 0, 0);
}

// ---------------------------------------------------------------- gw transpose: [2048][7] -> [7][2048]
__global__ void gwt_kernel(const float* __restrict__ gw, float* __restrict__ gwT) {
  int i = blockIdx.x * 256 + threadIdx.x;  // 56 blocks * 256 = 14336 exact
  float v = gw[i];
  int d = i / NUM_ROUTED;
  int e = i - d * NUM_ROUTED;
  gwT[e * DD + d] = v;
}

// ---------------------------------------------------------------- gate (4 waves/block, 4 tokens/wave)
__global__ void gate_kernel(const float* __restrict__ x, const float* __restrict__ gwT,
                            const float* __restrict__ gb, const float* __restrict__ bias,
                            int* __restrict__ counts, int* __restrict__ tok_list,
                            float* __restrict__ tok_w) {
  __shared__ int lhist[NUM_ROUTED];
  __shared__ int lbase[NUM_ROUTED];
  __shared__ int ent_e[48];
  __shared__ int ent_pos[48];
  __shared__ int ent_t[48];
  __shared__ float ent_w[48];

  const int tid = threadIdx.x;
  const int wave = tid >> 6;
  const int lane = tid & 63;
  if (tid < NUM_ROUTED) lhist[tid] = 0;
  __syncthreads();

  for (int j = 0; j < 4; ++j) {
    const int t = blockIdx.x * 16 + wave * 4 + j;
    const float* xr = x + (size_t)t * DD;
    float acc[NUM_ROUTED] = {0.f, 0.f, 0.f, 0.f, 0.f, 0.f, 0.f};
#pragma unroll
    for (int it = 0; it < 8; ++it) {
      const int d0 = it * 256 + lane * 4;
      float4 xv = *(const float4*)(xr + d0);
#pragma unroll
      for (int e = 0; e < NUM_ROUTED; ++e) {
        float4 g = *(const float4*)(gwT + e * DD + d0);
        acc[e] += xv.x * g.x + xv.y * g.y + xv.z * g.z + xv.w * g.w;
      }
    }
#pragma unroll
    for (int off = 32; off > 0; off >>= 1)
#pragma unroll
      for (int e = 0; e < NUM_ROUTED; ++e) acc[e] += __shfl_down(acc[e], off);
    if (lane == 0) {
      float l[NUM_ROUTED], p[NUM_ROUTED], b[NUM_ROUTED];
      float m = -1e30f;
#pragma unroll
      for (int e = 0; e < NUM_ROUTED; ++e) { l[e] = acc[e] + gb[e]; m = fmaxf(m, l[e]); }
      float s = 0.f;
#pragma unroll
      for (int e = 0; e < NUM_ROUTED; ++e) { p[e] = __expf(l[e] - m); s += p[e]; }
      float inv = 1.f / s;
#pragma unroll
      for (int e = 0; e < NUM_ROUTED; ++e) { p[e] *= inv; b[e] = p[e] + bias[e]; }
      int id[3]; float w[3]; float wsum = 0.f;
      bool used[NUM_ROUTED] = {false, false, false, false, false, false, false};
#pragma unroll
      for (int k = 0; k < 3; ++k) {
        int best = -1; float bv = -1e30f;
#pragma unroll
        for (int e = 0; e < NUM_ROUTED; ++e)
          if (!used[e] && b[e] > bv) { bv = b[e]; best = e; }
        used[best] = true; id[k] = best; w[k] = p[best]; wsum += w[k];
      }
      float wn = 1.f / wsum;
#pragma unroll
      for (int k = 0; k < 3; ++k) {
        int e = id[k];
        int pos = atomicAdd(&lhist[e], 1);
        int slot = (wave * 4 + j) * 3 + k;
        ent_e[slot] = e; ent_pos[slot] = pos; ent_t[slot] = t; ent_w[slot] = w[k] * wn;
      }
    }
  }
  __syncthreads();
  if (tid < NUM_ROUTED) lbase[tid] = atomicAdd(&counts[tid], lhist[tid]);
  __syncthreads();
  if (tid < 48) {
    int e = ent_e[tid];
    int pdst = lbase[e] + ent_pos[tid];
    tok_list[e * NTOK + pdst] = ent_t[tid];
    tok_w[e * NTOK + pdst] = ent_w[tid];
  }
}

// ---------------------------------------------------------------- x fp32 -> fp16
__global__ void split_x_kernel(const float* __restrict__ x, unsigned short* __restrict__ xh) {
  size_t i = ((size_t)blockIdx.x * 256 + threadIdx.x) * 4;
  float4 v = *(const float4*)(x + i);
  ushort4 h;
  h.x = f2h(v.x); h.y = f2h(v.y); h.z = f2h(v.z); h.w = f2h(v.w);
  *(ushort4*)(xh + i) = h;
}

// ---------------------------------------------------------------- transpose+convert 3 weight mats (2048x2048)
__global__ void split3_kernel(const float* __restrict__ s0, const float* __restrict__ s1,
                              const float* __restrict__ s2,
                              unsigned short* __restrict__ d0, unsigned short* __restrict__ d1,
                              unsigned short* __restrict__ d2) {
  const float* src = (blockIdx.z == 0) ? s0 : (blockIdx.z == 1) ? s1 : s2;
  unsigned short* dh = (blockIdx.z == 0) ? d0 : (blockIdx.z == 1) ? d1 : d2;
  __shared__ float t[64][65];
  const int tc = threadIdx.x & 15;   // col/4
  const int tr = threadIdx.x >> 4;   // row (16 per pass)
  const int r0 = blockIdx.y * 64, c0 = blockIdx.x * 64;
#pragma unroll
  for (int p = 0; p < 4; ++p) {
    int r = tr + p * 16;
    float4 v = *(const float4*)(src + (size_t)(r0 + r) * 2048 + c0 + tc * 4);
    t[r][tc * 4 + 0] = v.x;
    t[r][tc * 4 + 1] = v.y;
    t[r][tc * 4 + 2] = v.z;
    t[r][tc * 4 + 3] = v.w;
  }
  __syncthreads();
#pragma unroll
  for (int p = 0; p < 4; ++p) {
    int c = tr + p * 16;  // output row (= source col)
    ushort4 o4;
    o4.x = f2h(t[tc * 4 + 0][c]);
    o4.y = f2h(t[tc * 4 + 1][c]);
    o4.z = f2h(t[tc * 4 + 2][c]);
    o4.w = f2h(t[tc * 4 + 3][c]);
    *(ushort4*)(dh + (size_t)(c0 + c) * 2048 + r0 + tc * 4) = o4;
  }
}

// ---------------------------------------------------------------- GEMM1: x @ (W1 | Wg) + SwiGLU -> act
// R3 winner config: 256 threads, 4 waves, tile 128x64, BK=64.
// Grid is (n_tiles, m_tiles): consecutive blocks share the A-panel (L2 reuse).
template <bool GATHER>
__global__ __launch_bounds__(256, 2) void gemm1_kernel(
    const unsigned short* __restrict__ xh, const unsigned short* __restrict__ b1_g,
    const unsigned short* __restrict__ bg_g, const int* __restrict__ count,
    const int* __restrict__ tok_list, unsigned short* __restrict__ act) {
  const int n_rows = GATHER ? *count : NTOK;
  const int row0 = blockIdx.y * BM;
  if (row0 >= n_rows) return;
  const int n0 = blockIdx.x * BN;

  __shared__ alignas(16) unsigned short Ah[BM * BK];
  __shared__ alignas(16) unsigned short B1h[BN * BK], Bgh[BN * BK];

  const int tid = threadIdx.x;
  const int lane = tid & 63;
  const int wid = tid >> 6;
  const int sr = lane >> 3;
  const int sc = (lane & 7) * 8;

  long gr[4];
#pragma unroll
  for (int i = 0; i < 4; ++i) {
    int ar = row0 + wid * 32 + i * 8 + sr;
    int src_row;
    if (GATHER) src_row = tok_list[ar < n_rows ? ar : (n_rows - 1)];
    else src_row = ar;
    gr[i] = (long)src_row * DD + sc;
  }
  long br[2];
#pragma unroll
  for (int j = 0; j < 2; ++j) br[j] = (long)(n0 + wid * 16 + j * 8 + sr) * DD + sc;

  const int wm = (wid >> 1) * 64;
  const int wn = (wid & 1) * 32;

  f32x4 acc1[4][2] = {};
  f32x4 accg[4][2] = {};

  for (int k0 = 0; k0 < DD; k0 += BK) {
#pragma unroll
    for (int i = 0; i < 4; ++i) {
      int ldst = (wid * 32 + i * 8 + sr) * BK + sc;
      gload16(xh + gr[i] + k0, &Ah[ldst]);
    }
#pragma unroll
    for (int j = 0; j < 2; ++j) {
      int ldst = (wid * 16 + j * 8 + sr) * BK + sc;
      gload16(b1_g + br[j] + k0, &B1h[ldst]);
      gload16(bg_g + br[j] + k0, &Bgh[ldst]);
    }
    __syncthreads();
#pragma unroll
    for (int ks = 0; ks < 2; ++ks) {
      const int ko = ks * 32 + (lane >> 4) * 8;
      f16x8 a_h[4];
#pragma unroll
      for (int mi = 0; mi < 4; ++mi) {
        int off = (wm + mi * 16 + (lane & 15)) * BK + ko;
        a_h[mi] = *(const f16x8*)&Ah[off];
      }
      f16x8 u1[2], ug[2];
#pragma unroll
      for (int ni = 0; ni < 2; ++ni) {
        int off = (wn + ni * 16 + (lane & 15)) * BK + ko;
        u1[ni] = *(const f16x8*)&B1h[off];
        ug[ni] = *(const f16x8*)&Bgh[off];
      }
#pragma unroll
      for (int mi = 0; mi < 4; ++mi)
#pragma unroll
        for (int ni = 0; ni < 2; ++ni) {
          acc1[mi][ni] = MFMA16(a_h[mi], u1[ni], acc1[mi][ni]);
          accg[mi][ni] = MFMA16(a_h[mi], ug[ni], accg[mi][ni]);
        }
    }
    __syncthreads();
  }
  // SwiGLU epilogue -> act fp16
#pragma unroll
  for (int mi = 0; mi < 4; ++mi)
#pragma unroll
    for (int ni = 0; ni < 2; ++ni)
#pragma unroll
      for (int r = 0; r < 4; ++r) {
        int m = wm + mi * 16 + (lane >> 4) * 4 + r;
        int nn = wn + ni * 16 + (lane & 15);
        float h1 = acc1[mi][ni][r];
        float hg = accg[mi][ni][r];
        float a = (h1 / (1.f + __expf(-h1))) * hg;  // silu(h1)*hg
        act[(long)(row0 + m) * HH + n0 + nn] = f2h(a);
      }
}

// ---------------------------------------------------------------- GEMM2: act @ W2 -> out (m103 config)
// 256 threads, 4 waves (2x2); tile 128x128; per-wave 64x64. Grid (n_tiles, m_tiles).
template <bool ROUTED>
__global__ __launch_bounds__(256, 3) void gemm2_kernel(
    const unsigned short* __restrict__ ah, const unsigned short* __restrict__ bh_g,
    const int* __restrict__ count, const int* __restrict__ tok_list,
    const float* __restrict__ tok_w, float* __restrict__ out) {
  const int n_rows = ROUTED ? *count : NTOK;
  const int row0 = blockIdx.y * 128;
  if (row0 >= n_rows) return;
  const int n0 = blockIdx.x * 128;

  __shared__ alignas(16) unsigned short Ah[128 * 64];
  __shared__ alignas(16) unsigned short Bh[128 * 64];

  const int tid = threadIdx.x;
  const int lane = tid & 63;
  const int wid = tid >> 6;
  const int wm = (wid >> 1) * 64;
  const int wn = (wid & 1) * 64;

  const int sxr = tid >> 3;          // 0..31
  const int sxc = (tid & 7) * 8;
  int ga[4], gb[4], ls[4];
#pragma unroll
  for (int p = 0; p < 4; ++p) {
    ga[p] = (row0 + p * 32 + sxr) * HH + sxc;   // act rows in-buffer even past n_rows (finite poison)
    gb[p] = (n0 + p * 32 + sxr) * HH + sxc;
    ls[p] = p * 32 * 64 + tid * 8;
  }

  f32x4 acc[4][4] = {};
  const int l15 = lane & 15;
  const int khalf = (lane >> 4) * 8;

  for (int k0 = 0; k0 < HH; k0 += 64) {
#pragma unroll
    for (int p = 0; p < 4; ++p) gload16(ah + ga[p] + k0, &Ah[ls[p]]);
#pragma unroll
    for (int p = 0; p < 4; ++p) gload16(bh_g + gb[p] + k0, &Bh[ls[p]]);
    __syncthreads();
#pragma unroll
    for (int ks = 0; ks < 2; ++ks) {
      const int ko = ks * 32 + khalf;
      f16x8 a_h[4];
#pragma unroll
      for (int mi = 0; mi < 4; ++mi)
        a_h[mi] = *(const f16x8*)&Ah[(wm + mi * 16 + l15) * 64 + ko];
      f16x8 b_h[4];
#pragma unroll
      for (int ni = 0; ni < 4; ++ni)
        b_h[ni] = *(const f16x8*)&Bh[(wn + ni * 16 + l15) * 64 + ko];
#pragma unroll
      for (int mi = 0; mi < 4; ++mi)
#pragma unroll
        for (int ni = 0; ni < 4; ++ni)
          acc[mi][ni] = MFMA16(a_h[mi], b_h[ni], acc[mi][ni]);
    }
    __syncthreads();
  }
#pragma unroll
  for (int mi = 0; mi < 4; ++mi)
#pragma unroll
    for (int ni = 0; ni < 4; ++ni)
#pragma unroll
      for (int r = 0; r < 4; ++r) {
        int m = wm + mi * 16 + (lane >> 4) * 4 + r;
        int nn = wn + ni * 16 + l15;
        int rg = row0 + m;
        float val = acc[mi][ni][r];
        if (ROUTED) {
          if (rg < n_rows) {
            int t = tok_list[rg];
            float w = tok_w[rg];
            out[t * DD + n0 + nn] += w * val;  // unique (t,col) per launch; stream-ordered
          }
        } else {
          out[rg * DD + n0 + nn] = val;
        }
      }
}

// ---------------------------------------------------------------- launch
extern "C" void kernel_launch(void* const* d_in, const int* in_sizes, int n_in,
                              void* d_out, int out_size, void* d_ws, size_t ws_size,
                              hipStream_t stream) {
  const float* x    = (const float*)d_in[0];
  const float* W1   = (const float*)d_in[1];
  const float* Wg   = (const float*)d_in[2];
  const float* W2   = (const float*)d_in[3];
  const float* Ws1  = (const float*)d_in[4];
  const float* Wsg  = (const float*)d_in[5];
  const float* Ws2  = (const float*)d_in[6];
  const float* gw   = (const float*)d_in[7];
  const float* gb   = (const float*)d_in[8];
  const float* bias = (const float*)d_in[9];
  float* out = (float*)d_out;

  char* p = (char*)d_ws;
  size_t off = 0;
  auto alloc = [&](size_t bytes) {
    void* r = p + off;
    off = (off + bytes + 255) & ~(size_t)255;
    return r;
  };
  int* counts         = (int*)alloc(32);
  int* tok_list       = (int*)alloc((size_t)NUM_ROUTED * NTOK * 4);
  float* tok_w        = (float*)alloc((size_t)NUM_ROUTED * NTOK * 4);
  float* gwT          = (float*)alloc((size_t)NUM_ROUTED * DD * 4);
  unsigned short* xh  = (unsigned short*)alloc((size_t)NTOK * DD * 2);
  unsigned short* b1  = (unsigned short*)alloc((size_t)DD * HH * 2);
  unsigned short* bg  = (unsigned short*)alloc((size_t)DD * HH * 2);
  unsigned short* b2  = (unsigned short*)alloc((size_t)HH * DD * 2);
  unsigned short* act = (unsigned short*)alloc((size_t)NTOK * HH * 2);
  if (off > ws_size) return;  // workspace too small — fail loudly via validation

  hipMemsetAsync(counts, 0, 32, stream);
  gwt_kernel<<<56, 256, 0, stream>>>(gw, gwT);
  gate_kernel<<<NTOK / 16, 256, 0, stream>>>(x, gwT, gb, bias, counts, tok_list, tok_w);
  split_x_kernel<<<(NTOK * DD / 4) / 256, 256, 0, stream>>>(x, xh);

  // shared expert: plain store covers all of out (no memset needed)
  split3_kernel<<<dim3(32, 32, 3), 256, 0, stream>>>(Ws1, Wsg, Ws2, b1, bg, b2);
  gemm1_kernel<false><<<dim3(32, 64), 256, 0, stream>>>(xh, b1, bg, nullptr, nullptr, act);
  gemm2_kernel<false><<<dim3(16, 64), 256, 0, stream>>>(act, b2, nullptr, nullptr, nullptr, out);

  for (int e = 0; e < NUM_ROUTED; ++e) {
    size_t wo = (size_t)e * DD * HH;
    split3_kernel<<<dim3(32, 32, 3), 256, 0, stream>>>(W1 + wo, Wg + wo, W2 + wo, b1, bg, b2);
    gemm1_kernel<true><<<dim3(32, 64), 256, 0, stream>>>(xh, b1, bg, counts + e,
                                                         tok_list + e * NTOK, act);
    gemm2_kernel<true><<<dim3(16, 64), 256, 0, stream>>>(act, b2, counts + e,
                                                         tok_list + e * NTOK,
                                                         tok_w + e * NTOK, out);
  }
}